// Round 4
// baseline (736.267 us; speedup 1.0000x reference)
//
#include <hip/hip_runtime.h>
#include <math.h>

// Fused attention block: QKV proj -> per-head RMSNorm -> RoPE (+q_gain) ->
// GQA causal flash attention -> output proj.  FP32 I/O, bf16 MFMA internal.
//
// Shapes: B=4 T=2048 H=16 KVH=4 HD=128 D=2048 KVD=512.
//
// R4 changes vs R3 (attn 234us: MfmaUtil 12.5%, VALUBusy 27%, HBM 14% ->
// latency/overhead-bound, nothing saturated):
//  - attn Q-tile 128 rows/block (2 groups of 16 per wave): 2x MFMA per
//    staged K/V tile, half the barriers/staging per unit work; kf/vf LDS
//    fragments shared across groups.
//  - S computed TRANSPOSED (mfma(kf,qf) -> col=qrow,row=kv): P values per
//    lane are 4 consecutive kv -> packed ds_write_b64 (8/wave/jt) replaces
//    32 scalar ds_write_b16; lsum becomes a per-lane scalar.
//  - diagonal/inactive groups handled purely by -inf masking (p=0), no
//    divergent MFMA predication.

typedef float f32x4 __attribute__((ext_vector_type(4)));
typedef __bf16 bf16x8 __attribute__((ext_vector_type(8)));
typedef __bf16 bf16x4 __attribute__((ext_vector_type(4)));

__device__ __forceinline__ void load_lds16(const __bf16* g, __bf16* l) {
    __builtin_amdgcn_global_load_lds(
        (const __attribute__((address_space(1))) void*)g,
        (__attribute__((address_space(3))) void*)l, 16, 0, 0);
}

// ---------------------------------------------------------------------------
// fp32 -> bf16 conversion (n divisible by 4)
// ---------------------------------------------------------------------------
__global__ __launch_bounds__(256) void cvt_f32_bf16(
    const float* __restrict__ src, __bf16* __restrict__ dst, int n)
{
    int i = (blockIdx.x * 256 + threadIdx.x) * 4;
    if (i < n) {
        float4 v = *(const float4*)(src + i);
        bf16x4 o = {(__bf16)v.x, (__bf16)v.y, (__bf16)v.z, (__bf16)v.w};
        *(bf16x4*)(dst + i) = o;
    }
}

// ---------------------------------------------------------------------------
// GEMM: C[M][N] = A[M][K] * W[N][K]^T   (row-major, bf16 in, OutT out)
// 128x128 tile, BK=32, 256 threads (4 waves, each 64x64 quadrant).
// ---------------------------------------------------------------------------
template <typename OutT>
__global__ __launch_bounds__(256) void gemm_bt(
    const __bf16* __restrict__ A, const __bf16* __restrict__ W,
    OutT* __restrict__ C, int M, int N, int K)
{
    const int bn = blockIdx.x, bm = blockIdx.y;
    const int tid = threadIdx.x;
    const int wave = tid >> 6, lane = tid & 63;
    const int quad = lane >> 4, l16 = lane & 15;

    __shared__ __bf16 As[128 * 32];
    __shared__ __bf16 Ws[128 * 32];

    const int wm = (wave & 1) * 64;
    const int wn = (wave >> 1) * 64;

    f32x4 acc[4][4] = {};

    const int srow = wave * 16 + (lane >> 2);   // + r*64
    const int scol = (lane & 3) * 8;

    const __bf16* Ag = A + (size_t)(bm * 128) * K + scol;
    const __bf16* Wg = W + (size_t)(bn * 128) * K + scol;

    for (int k0 = 0; k0 < K; k0 += 32) {
        __syncthreads();
#pragma unroll
        for (int r = 0; r < 2; ++r) {
            load_lds16(Ag + (size_t)(srow + r * 64) * K + k0, As + (r * 4 + wave) * 512);
            load_lds16(Wg + (size_t)(srow + r * 64) * K + k0, Ws + (r * 4 + wave) * 512);
        }
        __syncthreads();

        bf16x8 af[4], wf[4];
#pragma unroll
        for (int i = 0; i < 4; ++i) {
            af[i] = *(const bf16x8*)(As + (wm + i * 16 + l16) * 32 + quad * 8);
            wf[i] = *(const bf16x8*)(Ws + (wn + i * 16 + l16) * 32 + quad * 8);
        }
#pragma unroll
        for (int mi = 0; mi < 4; ++mi)
#pragma unroll
            for (int ni = 0; ni < 4; ++ni)
                acc[mi][ni] = __builtin_amdgcn_mfma_f32_16x16x32_bf16(
                    af[mi], wf[ni], acc[mi][ni], 0, 0, 0);
    }

    // epilogue: C/D layout col=l16, row=quad*4+r
#pragma unroll
    for (int mi = 0; mi < 4; ++mi) {
#pragma unroll
        for (int r = 0; r < 4; ++r) {
            int row = bm * 128 + wm + mi * 16 + quad * 4 + r;
            OutT* Cp = C + (size_t)row * N + bn * 128 + wn + l16;
#pragma unroll
            for (int ni = 0; ni < 4; ++ni)
                Cp[ni * 16] = (OutT)acc[mi][ni][r];
        }
    }
}

// ---------------------------------------------------------------------------
// Per-head RMSNorm + RoPE (+ q_gain).  One wave per 128-elem head row.
// q: [B*T][2048] (16 heads).  kv: [B*T][1024], cols 0..511 = k heads.
// ---------------------------------------------------------------------------
__global__ __launch_bounds__(256) void qk_norm_rope(
    __bf16* __restrict__ q, __bf16* __restrict__ kv,
    const float* __restrict__ q_gain)
{
    const int row = blockIdx.x * 4 + (threadIdx.x >> 6);
    const int lane = threadIdx.x & 63;
    const int BTH = 4 * 2048 * 16;

    __bf16* base;
    int t;
    float gain;
    if (row < BTH) {
        int bt = row >> 4, h = row & 15;
        base = q + (size_t)bt * 2048 + h * 128;
        t = bt & 2047;
        gain = q_gain[h];
    } else {
        int r2 = row - BTH;
        int bt = r2 >> 2, kvh = r2 & 3;
        base = kv + (size_t)bt * 1024 + kvh * 128;
        t = bt & 2047;
        gain = 1.0f;
    }

    float x0 = (float)base[lane];        // d = lane
    float x1 = (float)base[lane + 64];   // d = lane + 64

    float ss = x0 * x0 + x1 * x1;
#pragma unroll
    for (int off = 32; off; off >>= 1) ss += __shfl_xor(ss, off);
    float inv = rsqrtf(ss * (1.0f / 128.0f) + 1.1920928955078125e-07f);
    x0 *= inv; x1 *= inv;

    float freq = exp2f(-(float)lane * 0.20762050593046013f);
    float ang = (float)t * freq;
    float s, c;
    sincosf(ang, &s, &c);
    float o0 = x0 * c - x1 * s;
    float o1 = x1 * c + x0 * s;
    base[lane]      = (__bf16)(o0 * gain);
    base[lane + 64] = (__bf16)(o1 * gain);
}

// ---------------------------------------------------------------------------
// V transpose: vt[b][c][t] = kv[b][t][512 + c]   (c = kvh*128+d in [0,512))
// ---------------------------------------------------------------------------
__global__ __launch_bounds__(256) void transpose_v(
    const __bf16* __restrict__ kv, __bf16* __restrict__ vtout)
{
    __shared__ __bf16 tile[64][65];
    const int b = blockIdx.z;
    const int t0 = blockIdx.x * 64, c0 = blockIdx.y * 64;
    const __bf16* vb = kv + (size_t)b * 2048 * 1024 + 512;
    __bf16* vtb = vtout + (size_t)b * 512 * 2048;
    const int j = threadIdx.x & 63;
    const int r0 = threadIdx.x >> 6;
#pragma unroll
    for (int i = 0; i < 16; ++i) {
        int r = r0 + i * 4;
        tile[r][j] = vb[(size_t)(t0 + r) * 1024 + c0 + j];
    }
    __syncthreads();
#pragma unroll
    for (int i = 0; i < 16; ++i) {
        int r = r0 + i * 4;
        vtb[(size_t)(c0 + r) * 2048 + t0 + j] = tile[j][r];
    }
}

// ---------------------------------------------------------------------------
// Flash attention (causal, GQA).  Block = (128-row q tile, b*H+h), 256 thr.
// Each wave owns 32 q-rows (2 groups of 16).  S computed transposed.
// ---------------------------------------------------------------------------
__global__ __launch_bounds__(256, 3) void attn(
    const __bf16* __restrict__ q, const __bf16* __restrict__ kv,
    const __bf16* __restrict__ vt, __bf16* __restrict__ y,
    const float* __restrict__ q_gain)
{
    const int qtp = 15 - blockIdx.x;  // big tiles launch first
    const int bh = blockIdx.y;
    const int b = bh >> 4, h = bh & 15, kvh = h >> 2;
    const int tid = threadIdx.x;
    const int wave = tid >> 6, lane = tid & 63;
    const int quad = lane >> 4, l16 = lane & 15;

    __shared__ __bf16 Ks[64 * 128];    // [kv_row][d]   16B chunk c at c^(row&15)
    __shared__ __bf16 Vts[128 * 64];   // [d][kv_row]   16B chunk c at c^(row&7)
    __shared__ __bf16 Ps[8 * 16 * 64]; // [wave*2+g][qrow][kv] chunk c^(qrow&7)

    const int qt0 = qtp * 128;
    const int wr0 = wave * 32;         // wave's first q-row (local)

    // Q fragments straight from global (B-operand: 8 contiguous bf16 / lane)
    bf16x8 qf[2][4];
#pragma unroll
    for (int g = 0; g < 2; ++g) {
        const size_t qrow =
            ((size_t)b * 2048 + qt0 + wr0 + g * 16 + l16) * 2048 + h * 128;
#pragma unroll
        for (int t = 0; t < 4; ++t)
            qf[g][t] = *(const bf16x8*)(q + qrow + t * 32 + quad * 8);
    }

    f32x4 oacc[2][8] = {};
    float lsum[2] = {0.f, 0.f};

    const float sm_scale = 0.12754635f;  // 1/sqrt(128) * log2(e)
    const float mb = 11.5f * fabsf(q_gain[h]) * sm_scale;

    const size_t kbase = (size_t)b * 2048 * 1024 + kvh * 128;   // stride 1024
    const size_t vtbase = (size_t)(b * 4 + kvh) * 128 * 2048;   // stride 2048

    const int rowK = lane >> 4, pcK = lane & 15;
    const int rowV = lane >> 3, pcV = lane & 7;

    const int jmax = 2 * qtp + 1;
    for (int jt = 0; jt <= jmax; ++jt) {
        const int j0 = jt * 64;
        __syncthreads();
#pragma unroll
        for (int r = 0; r < 4; ++r) {
            int rrK = (r * 4 + wave) * 4 + rowK;
            int cK = pcK ^ (rrK & 15);
            load_lds16(kv + kbase + (size_t)(j0 + rrK) * 1024 + cK * 8,
                       Ks + (r * 4 + wave) * 512);
            int rrV = (r * 4 + wave) * 8 + rowV;
            int cV = pcV ^ (rrV & 7);
            load_lds16(vt + vtbase + (size_t)rrV * 2048 + j0 + cV * 8,
                       Vts + (r * 4 + wave) * 512);
        }
        __syncthreads();

        // S^T strips: D[m=kv 64][n=qrow 16] per group; kf shared.
        f32x4 s0[4] = {}, s1[4] = {};
#pragma unroll
        for (int nt = 0; nt < 4; ++nt)
#pragma unroll
            for (int t = 0; t < 4; ++t) {
                bf16x8 kf = *(const bf16x8*)(
                    Ks + (nt * 16 + l16) * 128 + ((t * 4 + quad) ^ l16) * 8);
                s0[nt] = __builtin_amdgcn_mfma_f32_16x16x32_bf16(
                    kf, qf[0][t], s0[nt], 0, 0, 0);
                s1[nt] = __builtin_amdgcn_mfma_f32_16x16x32_bf16(
                    kf, qf[1][t], s1[nt], 0, 0, 0);
            }

        // causal mask (covers diagonal AND fully-inactive groups: p -> 0)
        if (j0 + 63 > qt0 + wr0) {
#pragma unroll
            for (int nt = 0; nt < 4; ++nt)
#pragma unroll
                for (int r = 0; r < 4; ++r) {
                    int kvg = j0 + nt * 16 + quad * 4 + r;
                    if (kvg > qt0 + wr0 + l16)      s0[nt][r] = -3.0e38f;
                    if (kvg > qt0 + wr0 + 16 + l16) s1[nt][r] = -3.0e38f;
                }
        }

        // exp + lsum + packed P write (4 consecutive kv per lane -> b64)
#pragma unroll
        for (int g = 0; g < 2; ++g) {
            __bf16* Pw = Ps + (wave * 2 + g) * 1024;
#pragma unroll
            for (int nt = 0; nt < 4; ++nt) {
                f32x4& s = (g == 0) ? s0[nt] : s1[nt];
                float p0 = exp2f(s[0] * sm_scale - mb);
                float p1 = exp2f(s[1] * sm_scale - mb);
                float p2 = exp2f(s[2] * sm_scale - mb);
                float p3 = exp2f(s[3] * sm_scale - mb);
                lsum[g] += (p0 + p1) + (p2 + p3);
                bf16x4 pk = {(__bf16)p0, (__bf16)p1, (__bf16)p2, (__bf16)p3};
                *(bf16x4*)(Pw + l16 * 64 +
                           (((nt * 2 + (quad >> 1)) ^ (l16 & 7)) * 8) +
                           (quad & 1) * 4) = pk;
            }
        }

        // PV: vf shared across groups
#pragma unroll
        for (int kt = 0; kt < 2; ++kt) {
            bf16x8 pf0 = *(const bf16x8*)(
                Ps + (wave * 2 + 0) * 1024 + l16 * 64 +
                ((kt * 4 + quad) ^ (l16 & 7)) * 8);
            bf16x8 pf1 = *(const bf16x8*)(
                Ps + (wave * 2 + 1) * 1024 + l16 * 64 +
                ((kt * 4 + quad) ^ (l16 & 7)) * 8);
#pragma unroll
            for (int vn = 0; vn < 8; ++vn) {
                bf16x8 vf = *(const bf16x8*)(
                    Vts + (vn * 16 + l16) * 64 + ((kt * 4 + quad) ^ (l16 & 7)) * 8);
                oacc[0][vn] = __builtin_amdgcn_mfma_f32_16x16x32_bf16(
                    pf0, vf, oacc[0][vn], 0, 0, 0);
                oacc[1][vn] = __builtin_amdgcn_mfma_f32_16x16x32_bf16(
                    pf1, vf, oacc[1][vn], 0, 0, 0);
            }
        }
    }

    // epilogue: y[b][t][h*128+d]
#pragma unroll
    for (int g = 0; g < 2; ++g) {
        float ls = lsum[g];
        ls += __shfl_xor(ls, 16);
        ls += __shfl_xor(ls, 32);   // lanes 0..15 hold total for qrow=l16
#pragma unroll
        for (int r = 0; r < 4; ++r) {
            float inv = 1.0f / __shfl(ls, quad * 4 + r);
            int yrow = qt0 + wr0 + g * 16 + quad * 4 + r;
            __bf16* yp = y + ((size_t)(b * 2048 + yrow)) * 2048 + h * 128 + l16;
#pragma unroll
            for (int vn = 0; vn < 8; ++vn)
                yp[vn * 16] = (__bf16)(oacc[g][vn][r] * inv);
        }
    }
}

// ---------------------------------------------------------------------------
extern "C" void kernel_launch(void* const* d_in, const int* in_sizes, int n_in,
                              void* d_out, int out_size, void* d_ws, size_t ws_size,
                              hipStream_t stream) {
    const float* x     = (const float*)d_in[0];
    const float* Wq    = (const float*)d_in[1];
    const float* Wk    = (const float*)d_in[2];
    const float* Wv    = (const float*)d_in[3];
    const float* Wproj = (const float*)d_in[4];
    const float* qgain = (const float*)d_in[5];
    float* outp = (float*)d_out;

    // workspace layout (bf16 elems)
    __bf16* xb  = (__bf16*)d_ws;          // 16777216
    __bf16* Wqb = xb  + 16777216;         // 4194304
    __bf16* Wkb = Wqb + 4194304;          // 1048576  (Wkb+Wvb fused [1024][2048])
    __bf16* Wvb = Wkb + 1048576;          // 1048576
    __bf16* Wpb = Wvb + 1048576;          // 4194304
    __bf16* q   = Wpb + 4194304;          // 16777216
    __bf16* kvb = q   + 16777216;         // 8388608  [4*2048][1024]: k|v fused
    __bf16* vt  = kvb + 8388608;          // 4194304  [4][512][2048]
    __bf16* y   = q;                      // alias: 1:1 tile correspondence, safe

    dim3 blk(256);
    cvt_f32_bf16<<<dim3(16777216 / 1024), blk, 0, stream>>>(x, xb, 16777216);
    cvt_f32_bf16<<<dim3(4194304 / 1024), blk, 0, stream>>>(Wq, Wqb, 4194304);
    cvt_f32_bf16<<<dim3(1048576 / 1024), blk, 0, stream>>>(Wk, Wkb, 1048576);
    cvt_f32_bf16<<<dim3(1048576 / 1024), blk, 0, stream>>>(Wv, Wvb, 1048576);
    cvt_f32_bf16<<<dim3(4194304 / 1024), blk, 0, stream>>>(Wproj, Wpb, 4194304);

    gemm_bt<__bf16><<<dim3(16, 64), blk, 0, stream>>>(xb, Wqb, q, 8192, 2048, 2048);
    gemm_bt<__bf16><<<dim3(8, 64), blk, 0, stream>>>(xb, Wkb, kvb, 8192, 1024, 2048);
    qk_norm_rope<<<dim3((4 * 2048 * (16 + 4)) / 4), blk, 0, stream>>>(q, kvb, qgain);
    transpose_v<<<dim3(32, 8, 4), blk, 0, stream>>>(kvb, vt);
    attn<<<dim3(16, 64), blk, 0, stream>>>(q, kvb, vt, y, qgain);
    gemm_bt<float><<<dim3(16, 64), blk, 0, stream>>>(y, Wpb, outp, 8192, 2048, 2048);
}

// Round 5
// 660.530 us; speedup vs baseline: 1.1147x; 1.1147x over previous
//
#include <hip/hip_runtime.h>
#include <math.h>

// Fused attention block: QKV proj -> per-head RMSNorm -> RoPE (+q_gain) ->
// GQA causal flash attention -> output proj.  FP32 I/O, bf16 MFMA internal.
//
// Shapes: B=4 T=2048 H=16 KVH=4 HD=128 D=2048 KVD=512.
//
// R5 changes vs R4 (R4 REGRESSED: 128-row attn tile halved grid -> occupancy
// 13%, MfmaUtil 9%; reverted to R3's 64-row/2048-block attn):
//  - NEW: vectorized epilogues. R3/R4 counters showed attn WRITE_SIZE
//    128MB/92MB vs 32MB ideal -- scalar 2B stores at 32B stride cause
//    partial-line write amplification + write-allocate fetches. Both attn
//    and bf16-GEMM epilogues now round-trip accumulators through per-wave
//    XOR-swizzled LDS so every lane stores 16B contiguous.
//  - fp32 GEMM epilogue (proj) unchanged: 16 lanes x 4B = 64B/instr already.

typedef float f32x4 __attribute__((ext_vector_type(4)));
typedef __bf16 bf16x8 __attribute__((ext_vector_type(8)));
typedef __bf16 bf16x4 __attribute__((ext_vector_type(4)));

__device__ __forceinline__ void load_lds16(const __bf16* g, __bf16* l) {
    __builtin_amdgcn_global_load_lds(
        (const __attribute__((address_space(1))) void*)g,
        (__attribute__((address_space(3))) void*)l, 16, 0, 0);
}

// ---------------------------------------------------------------------------
// fp32 -> bf16 conversion (n divisible by 4)
// ---------------------------------------------------------------------------
__global__ __launch_bounds__(256) void cvt_f32_bf16(
    const float* __restrict__ src, __bf16* __restrict__ dst, int n)
{
    int i = (blockIdx.x * 256 + threadIdx.x) * 4;
    if (i < n) {
        float4 v = *(const float4*)(src + i);
        bf16x4 o = {(__bf16)v.x, (__bf16)v.y, (__bf16)v.z, (__bf16)v.w};
        *(bf16x4*)(dst + i) = o;
    }
}

// ---------------------------------------------------------------------------
// GEMM: C[M][N] = A[M][K] * W[N][K]^T   (row-major, bf16 in, OutT out)
// 128x128 tile, BK=32, 256 threads (4 waves, each 64x64 quadrant).
// bf16 output goes through a per-wave LDS transpose -> 16B/lane stores.
// ---------------------------------------------------------------------------
template <typename OutT>
__global__ __launch_bounds__(256) void gemm_bt(
    const __bf16* __restrict__ A, const __bf16* __restrict__ W,
    OutT* __restrict__ C, int M, int N, int K)
{
    const int bn = blockIdx.x, bm = blockIdx.y;
    const int tid = threadIdx.x;
    const int wave = tid >> 6, lane = tid & 63;
    const int quad = lane >> 4, l16 = lane & 15;

    __shared__ __bf16 smem[8192];      // As = smem[0:4096), Ws = smem[4096:8192)
    __bf16* As = smem;
    __bf16* Ws = smem + 4096;

    const int wm = (wave & 1) * 64;
    const int wn = (wave >> 1) * 64;

    f32x4 acc[4][4] = {};

    const int srow = wave * 16 + (lane >> 2);   // + r*64
    const int scol = (lane & 3) * 8;

    const __bf16* Ag = A + (size_t)(bm * 128) * K + scol;
    const __bf16* Wg = W + (size_t)(bn * 128) * K + scol;

    for (int k0 = 0; k0 < K; k0 += 32) {
        __syncthreads();
#pragma unroll
        for (int r = 0; r < 2; ++r) {
            load_lds16(Ag + (size_t)(srow + r * 64) * K + k0, As + (r * 4 + wave) * 512);
            load_lds16(Wg + (size_t)(srow + r * 64) * K + k0, Ws + (r * 4 + wave) * 512);
        }
        __syncthreads();

        bf16x8 af[4], wf[4];
#pragma unroll
        for (int i = 0; i < 4; ++i) {
            af[i] = *(const bf16x8*)(As + (wm + i * 16 + l16) * 32 + quad * 8);
            wf[i] = *(const bf16x8*)(Ws + (wn + i * 16 + l16) * 32 + quad * 8);
        }
#pragma unroll
        for (int mi = 0; mi < 4; ++mi)
#pragma unroll
            for (int ni = 0; ni < 4; ++ni)
                acc[mi][ni] = __builtin_amdgcn_mfma_f32_16x16x32_bf16(
                    af[mi], wf[ni], acc[mi][ni], 0, 0, 0);
    }

    __syncthreads();   // staging LDS reused by epilogue

    if constexpr (sizeof(OutT) == 2) {
        // per-wave 4KB region; C-layout in (scalar b16, swizzled), row-major
        // out (b128 reads conflict-free), 16B/lane global stores.
        __bf16* Es = smem + wave * 2048;
#pragma unroll
        for (int mi = 0; mi < 4; ++mi) {
#pragma unroll
            for (int ni = 0; ni < 4; ++ni)
#pragma unroll
                for (int r = 0; r < 4; ++r) {
                    int row = quad * 4 + r;
                    int c = (ni * 2 + (l16 >> 3)) ^ (row & 7);
                    Es[row * 64 + c * 8 + (l16 & 7)] = (__bf16)acc[mi][ni][r];
                }
#pragma unroll
            for (int p = 0; p < 2; ++p) {
                int row = p * 8 + (lane >> 3);
                int c = (lane & 7) ^ (row & 7);
                bf16x8 val = *(const bf16x8*)(Es + row * 64 + c * 8);
                int grow = bm * 128 + wm + mi * 16 + row;
                *(bf16x8*)((__bf16*)C + (size_t)grow * N + bn * 128 + wn +
                           (lane & 7) * 8) = val;
            }
        }
    } else {
        // fp32: 16 lanes x 4B = 64B contiguous per instr -- fine as-is
#pragma unroll
        for (int mi = 0; mi < 4; ++mi)
#pragma unroll
            for (int r = 0; r < 4; ++r) {
                int row = bm * 128 + wm + mi * 16 + quad * 4 + r;
                OutT* Cp = C + (size_t)row * N + bn * 128 + wn + l16;
#pragma unroll
                for (int ni = 0; ni < 4; ++ni)
                    Cp[ni * 16] = (OutT)acc[mi][ni][r];
            }
    }
}

// ---------------------------------------------------------------------------
// Per-head RMSNorm + RoPE (+ q_gain).  One wave per 128-elem head row.
// q: [B*T][2048] (16 heads).  kv: [B*T][1024], cols 0..511 = k heads.
// ---------------------------------------------------------------------------
__global__ __launch_bounds__(256) void qk_norm_rope(
    __bf16* __restrict__ q, __bf16* __restrict__ kv,
    const float* __restrict__ q_gain)
{
    const int row = blockIdx.x * 4 + (threadIdx.x >> 6);
    const int lane = threadIdx.x & 63;
    const int BTH = 4 * 2048 * 16;

    __bf16* base;
    int t;
    float gain;
    if (row < BTH) {
        int bt = row >> 4, h = row & 15;
        base = q + (size_t)bt * 2048 + h * 128;
        t = bt & 2047;
        gain = q_gain[h];
    } else {
        int r2 = row - BTH;
        int bt = r2 >> 2, kvh = r2 & 3;
        base = kv + (size_t)bt * 1024 + kvh * 128;
        t = bt & 2047;
        gain = 1.0f;
    }

    float x0 = (float)base[lane];        // d = lane
    float x1 = (float)base[lane + 64];   // d = lane + 64

    float ss = x0 * x0 + x1 * x1;
#pragma unroll
    for (int off = 32; off; off >>= 1) ss += __shfl_xor(ss, off);
    float inv = rsqrtf(ss * (1.0f / 128.0f) + 1.1920928955078125e-07f);
    x0 *= inv; x1 *= inv;

    float freq = exp2f(-(float)lane * 0.20762050593046013f);
    float ang = (float)t * freq;
    float s, c;
    sincosf(ang, &s, &c);
    float o0 = x0 * c - x1 * s;
    float o1 = x1 * c + x0 * s;
    base[lane]      = (__bf16)(o0 * gain);
    base[lane + 64] = (__bf16)(o1 * gain);
}

// ---------------------------------------------------------------------------
// V transpose: vt[b][c][t] = kv[b][t][512 + c]   (c = kvh*128+d in [0,512))
// ---------------------------------------------------------------------------
__global__ __launch_bounds__(256) void transpose_v(
    const __bf16* __restrict__ kv, __bf16* __restrict__ vtout)
{
    __shared__ __bf16 tile[64][65];
    const int b = blockIdx.z;
    const int t0 = blockIdx.x * 64, c0 = blockIdx.y * 64;
    const __bf16* vb = kv + (size_t)b * 2048 * 1024 + 512;
    __bf16* vtb = vtout + (size_t)b * 512 * 2048;
    const int j = threadIdx.x & 63;
    const int r0 = threadIdx.x >> 6;
#pragma unroll
    for (int i = 0; i < 16; ++i) {
        int r = r0 + i * 4;
        tile[r][j] = vb[(size_t)(t0 + r) * 1024 + c0 + j];
    }
    __syncthreads();
#pragma unroll
    for (int i = 0; i < 16; ++i) {
        int r = r0 + i * 4;
        vtb[(size_t)(c0 + r) * 2048 + t0 + j] = tile[j][r];
    }
}

// ---------------------------------------------------------------------------
// Flash attention (causal, GQA).  Block = (64-row qtile, b*H+h), 256 thr.
// R3 structure (2048 blocks, 40KB LDS) + vectorized y epilogue.
// ---------------------------------------------------------------------------
__global__ __launch_bounds__(256, 4) void attn(
    const __bf16* __restrict__ q, const __bf16* __restrict__ kv,
    const __bf16* __restrict__ vt, __bf16* __restrict__ y,
    const float* __restrict__ q_gain)
{
    const int qt = 31 - blockIdx.x;  // big blocks launch first
    const int bh = blockIdx.y;
    const int b = bh >> 4, h = bh & 15, kvh = h >> 2;
    const int tid = threadIdx.x;
    const int wave = tid >> 6, lane = tid & 63;
    const int quad = lane >> 4, l16 = lane & 15;

    __shared__ __bf16 Ks[64 * 128];    // [kv_row][d]  chunk c at c^(row&15)
    __shared__ __bf16 Vts[128 * 64];   // [d][kv_row]  chunk c at c^(row&7)
    __shared__ __bf16 Ps[4 * 16 * 64]; // per-wave [qrow][kv] chunk c^(row&7)

    const int qt0 = qt * 64;
    const int wq = wave * 16;   // this wave's 16 q-rows (local)

    // Q fragments straight from global (A-layout: 8 contiguous bf16 / lane)
    const size_t qrow = ((size_t)b * 2048 + qt0 + wq + l16) * 2048 + h * 128;
    bf16x8 qf[4];
#pragma unroll
    for (int t = 0; t < 4; ++t)
        qf[t] = *(const bf16x8*)(q + qrow + t * 32 + quad * 8);

    f32x4 oacc[8] = {};
    float lsum[4] = {0.f, 0.f, 0.f, 0.f};

    const float sm_scale = 0.12754635f;          // 1/sqrt(128) * log2(e)
    const float mfix = 11.5f * fabsf(q_gain[h]); // >= max possible score

    const size_t kbase = (size_t)b * 2048 * 1024 + kvh * 128;      // stride 1024
    const size_t vtbase = (size_t)(b * 4 + kvh) * 128 * 2048;      // stride 2048

    const int rowK = lane >> 4, pcK = lane & 15;
    const int rowV = lane >> 3, pcV = lane & 7;

    for (int jt = 0; jt <= qt; ++jt) {
        const int j0 = jt * 64;
        __syncthreads();
#pragma unroll
        for (int r = 0; r < 4; ++r) {
            int rrK = (r * 4 + wave) * 4 + rowK;
            int cK = pcK ^ (rrK & 15);
            load_lds16(kv + kbase + (size_t)(j0 + rrK) * 1024 + cK * 8,
                       Ks + (r * 4 + wave) * 512);
            int rrV = (r * 4 + wave) * 8 + rowV;
            int cV = pcV ^ (rrV & 7);
            load_lds16(vt + vtbase + (size_t)rrV * 2048 + j0 + cV * 8,
                       Vts + (r * 4 + wave) * 512);
        }
        __syncthreads();

        // S strip (16 q-rows x 64 kv-cols) for this wave
        f32x4 sacc[4] = {};
#pragma unroll
        for (int nt = 0; nt < 4; ++nt)
#pragma unroll
            for (int t = 0; t < 4; ++t) {
                bf16x8 kf = *(const bf16x8*)(
                    Ks + (nt * 16 + l16) * 128 + ((t * 4 + quad) ^ l16) * 8);
                sacc[nt] = __builtin_amdgcn_mfma_f32_16x16x32_bf16(
                    qf[t], kf, sacc[nt], 0, 0, 0);
            }

        if (jt == qt) {  // diagonal tile: causal mask
#pragma unroll
            for (int nt = 0; nt < 4; ++nt) {
                int kg = nt * 16 + l16;
#pragma unroll
                for (int r = 0; r < 4; ++r)
                    if (kg > wq + quad * 4 + r) sacc[nt][r] = -3.0e38f;
            }
        }

        // fixed-max exp; per-lane partial row sums (reduced once at end)
        float p[4][4];
#pragma unroll
        for (int nt = 0; nt < 4; ++nt)
#pragma unroll
            for (int r = 0; r < 4; ++r) {
                float pv = exp2f((sacc[nt][r] - mfix) * sm_scale);
                p[nt][r] = pv;
                lsum[r] += pv;
            }

        // P: C-layout -> LDS (swizzled) -> A-layout (per-wave, no barrier)
        __bf16* Pw = Ps + wave * 1024;
#pragma unroll
        for (int nt = 0; nt < 4; ++nt)
#pragma unroll
            for (int r = 0; r < 4; ++r) {
                int row = quad * 4 + r;
                int pc = (nt * 2 + (l16 >> 3)) ^ (row & 7);
                Pw[row * 64 + pc * 8 + (l16 & 7)] = (__bf16)p[nt][r];
            }

#pragma unroll
        for (int kt = 0; kt < 2; ++kt) {
            bf16x8 pf = *(const bf16x8*)(
                Pw + l16 * 64 + ((kt * 4 + quad) ^ (l16 & 7)) * 8);
#pragma unroll
            for (int vn = 0; vn < 8; ++vn) {
                bf16x8 vf = *(const bf16x8*)(
                    Vts + (vn * 16 + l16) * 64 + ((kt * 4 + quad) ^ (l16 & 7)) * 8);
                oacc[vn] = __builtin_amdgcn_mfma_f32_16x16x32_bf16(
                    pf, vf, oacc[vn], 0, 0, 0);
            }
        }
    }

    // final l reduction across the 16 lanes holding each row
#pragma unroll
    for (int r = 0; r < 4; ++r)
#pragma unroll
        for (int off = 8; off; off >>= 1) lsum[r] += __shfl_xor(lsum[r], off);

    // vectorized epilogue: stage normalized O through per-wave LDS
    // (C-layout scalar writes, swizzled; b128 reads; 16B/lane global stores)
    __syncthreads();                  // Ks no longer needed
    __bf16* Es = Ks + wave * 2048;    // 4KB per wave
#pragma unroll
    for (int r = 0; r < 4; ++r) {
        float inv = 1.0f / lsum[r];
        int row = quad * 4 + r;
#pragma unroll
        for (int vn = 0; vn < 8; ++vn) {
            int c = (vn * 2 + (l16 >> 3)) ^ (row & 15);
            Es[row * 128 + c * 8 + (l16 & 7)] = (__bf16)(oacc[vn][r] * inv);
        }
    }
    // same-wave LDS ordering: no barrier needed
#pragma unroll
    for (int p = 0; p < 4; ++p) {
        int row = p * 4 + quad;
        int c = l16 ^ (row & 15);
        bf16x8 val = *(const bf16x8*)(Es + row * 128 + c * 8);
        int yrow = qt0 + wq + row;
        *(bf16x8*)(y + ((size_t)(b * 2048 + yrow)) * 2048 + h * 128 + l16 * 8) = val;
    }
}

// ---------------------------------------------------------------------------
extern "C" void kernel_launch(void* const* d_in, const int* in_sizes, int n_in,
                              void* d_out, int out_size, void* d_ws, size_t ws_size,
                              hipStream_t stream) {
    const float* x     = (const float*)d_in[0];
    const float* Wq    = (const float*)d_in[1];
    const float* Wk    = (const float*)d_in[2];
    const float* Wv    = (const float*)d_in[3];
    const float* Wproj = (const float*)d_in[4];
    const float* qgain = (const float*)d_in[5];
    float* outp = (float*)d_out;

    // workspace layout (bf16 elems)
    __bf16* xb  = (__bf16*)d_ws;          // 16777216
    __bf16* Wqb = xb  + 16777216;         // 4194304
    __bf16* Wkb = Wqb + 4194304;          // 1048576  (Wkb+Wvb fused [1024][2048])
    __bf16* Wvb = Wkb + 1048576;          // 1048576
    __bf16* Wpb = Wvb + 1048576;          // 4194304
    __bf16* q   = Wpb + 4194304;          // 16777216
    __bf16* kvb = q   + 16777216;         // 8388608  [4*2048][1024]: k|v fused
    __bf16* vt  = kvb + 8388608;          // 4194304  [4][512][2048]
    __bf16* y   = q;                      // alias: 1:1 tile correspondence, safe

    dim3 blk(256);
    cvt_f32_bf16<<<dim3(16777216 / 1024), blk, 0, stream>>>(x, xb, 16777216);
    cvt_f32_bf16<<<dim3(4194304 / 1024), blk, 0, stream>>>(Wq, Wqb, 4194304);
    cvt_f32_bf16<<<dim3(1048576 / 1024), blk, 0, stream>>>(Wk, Wkb, 1048576);
    cvt_f32_bf16<<<dim3(1048576 / 1024), blk, 0, stream>>>(Wv, Wvb, 1048576);
    cvt_f32_bf16<<<dim3(4194304 / 1024), blk, 0, stream>>>(Wproj, Wpb, 4194304);

    gemm_bt<__bf16><<<dim3(16, 64), blk, 0, stream>>>(xb, Wqb, q, 8192, 2048, 2048);
    gemm_bt<__bf16><<<dim3(8, 64), blk, 0, stream>>>(xb, Wkb, kvb, 8192, 1024, 2048);
    qk_norm_rope<<<dim3((4 * 2048 * (16 + 4)) / 4), blk, 0, stream>>>(q, kvb, qgain);
    transpose_v<<<dim3(32, 8, 4), blk, 0, stream>>>(kvb, vt);
    attn<<<dim3(32, 64), blk, 0, stream>>>(q, kvb, vt, y, qgain);
    gemm_bt<float><<<dim3(16, 64), blk, 0, stream>>>(y, Wpb, outp, 8192, 2048, 2048);
}